// Round 1
// baseline (744.373 us; speedup 1.0000x reference)
//
#include <hip/hip_runtime.h>
#include <hip/hip_bf16.h>

#define FEAT 128

// ---------------- histogram of col (in-degree, without self-loop) ------------
__global__ void hist_kernel(const int* __restrict__ col, int* __restrict__ counts, int E) {
    int e = blockIdx.x * 256 + threadIdx.x;
    if (e < E) atomicAdd(&counts[col[e]], 1);
}

// ---------------- scan step 1: per-1024-chunk sums ---------------------------
__global__ __launch_bounds__(256) void scan_part(const int* __restrict__ counts,
                                                 int* __restrict__ bsum, int n) {
    __shared__ int s[256];
    int base = blockIdx.x * 1024;
    int t = threadIdx.x;
    int v = 0;
#pragma unroll
    for (int i = 0; i < 4; i++) {
        int idx = base + t * 4 + i;
        if (idx < n) v += counts[idx];
    }
    s[t] = v;
    __syncthreads();
    for (int o = 128; o > 0; o >>= 1) {
        if (t < o) s[t] += s[t + o];
        __syncthreads();
    }
    if (t == 0) bsum[blockIdx.x] = s[0];
}

// ---------------- scan step 2: exclusive scan of block sums (nb <= 128) ------
__global__ void scan_bsum(int* __restrict__ bsum, int nb) {
    __shared__ int s[128];
    int t = threadIdx.x;
    int v0 = (t < nb) ? bsum[t] : 0;
    s[t] = v0;
    __syncthreads();
    for (int o = 1; o < 128; o <<= 1) {
        int v = (t >= o) ? s[t - o] : 0;
        __syncthreads();
        s[t] += v;
        __syncthreads();
    }
    if (t < nb) bsum[t] = s[t] - v0;  // exclusive
}

// ---------------- scan step 3: final offsets + next[] + dinv -----------------
__global__ __launch_bounds__(256) void scan_final(const int* __restrict__ counts,
                                                  const int* __restrict__ bsum,
                                                  int* __restrict__ off, int* __restrict__ nxt,
                                                  float* __restrict__ dinv, int n) {
    __shared__ int s[256];
    int base = blockIdx.x * 1024;
    int t = threadIdx.x;
    int c[4];
    int sum = 0;
#pragma unroll
    for (int i = 0; i < 4; i++) {
        int idx = base + t * 4 + i;
        c[i] = (idx < n) ? counts[idx] : 0;
        sum += c[i];
    }
    int v0 = sum;
    s[t] = sum;
    __syncthreads();
    for (int o = 1; o < 256; o <<= 1) {
        int v = (t >= o) ? s[t - o] : 0;
        __syncthreads();
        s[t] += v;
        __syncthreads();
    }
    int excl = s[t] - v0 + bsum[blockIdx.x];
#pragma unroll
    for (int i = 0; i < 4; i++) {
        int idx = base + t * 4 + i;
        if (idx < n) {
            off[idx] = excl;
            nxt[idx] = excl;
            dinv[idx] = rsqrtf((float)(c[i] + 1));  // +1 = self loop
        }
        excl += c[i];
    }
    if (blockIdx.x == gridDim.x - 1 && t == 255) off[n] = excl;  // == E
}

// ---------------- CSR fill: group edges by destination (col) -----------------
__global__ void fill_kernel(const int* __restrict__ row, const int* __restrict__ col,
                            const float* __restrict__ dinv, int* __restrict__ nxt,
                            int* __restrict__ src, float* __restrict__ snrm, int E) {
    int e = blockIdx.x * 256 + threadIdx.x;
    if (e < E) {
        int c = col[e], r = row[e];
        int p = atomicAdd(&nxt[c], 1);
        src[p] = r;
        snrm[p] = dinv[r];
    }
}

// ---------------- fp32 GEMM: XW = A @ W (A: [n,128], W: [128,128]) -----------
// leaky != 0 applies leaky_relu(0.01) to A elements on load.
__global__ __launch_bounds__(256) void gemm_kernel(const float* __restrict__ A,
                                                   const float* __restrict__ W,
                                                   float* __restrict__ XW, int n, int leaky) {
    __shared__ float sA[16][68];   // [k][row], 64 rows (+pad)
    __shared__ float sB[16][132];  // [k][col], 128 cols (+pad)

    const int t = threadIdx.x;
    const int tx = t & 15;   // col group: cols tx*8 .. tx*8+7
    const int ty = t >> 4;   // row group: rows ty*4 .. ty*4+3
    const int row0 = blockIdx.x * 64;

    float acc[4][8];
#pragma unroll
    for (int i = 0; i < 4; i++)
#pragma unroll
        for (int j = 0; j < 8; j++) acc[i][j] = 0.f;

    for (int k0 = 0; k0 < FEAT; k0 += 16) {
        // A tile: 64x16 = 1024 elems, 4/thread
#pragma unroll
        for (int i = 0; i < 4; i++) {
            int idx = t + i * 256;
            int r = idx >> 4, k = idx & 15;
            int gr = row0 + r;
            float v = 0.f;
            if (gr < n) v = A[(size_t)gr * FEAT + k0 + k];
            if (leaky) v = (v >= 0.f) ? v : 0.01f * v;
            sA[k][r] = v;
        }
        // W tile: 16x128 = 2048 elems, 8/thread
#pragma unroll
        for (int i = 0; i < 8; i++) {
            int idx = t + i * 256;
            int k = idx >> 7, c = idx & 127;
            sB[k][c] = W[(size_t)(k0 + k) * FEAT + c];
        }
        __syncthreads();
#pragma unroll
        for (int k = 0; k < 16; k++) {
            float a[4], b[8];
#pragma unroll
            for (int i = 0; i < 4; i++) a[i] = sA[k][ty * 4 + i];
#pragma unroll
            for (int j = 0; j < 8; j++) b[j] = sB[k][tx * 8 + j];
#pragma unroll
            for (int i = 0; i < 4; i++)
#pragma unroll
                for (int j = 0; j < 8; j++) acc[i][j] += a[i] * b[j];
        }
        __syncthreads();
    }
#pragma unroll
    for (int i = 0; i < 4; i++) {
        int gr = row0 + ty * 4 + i;
        if (gr < n) {
#pragma unroll
            for (int j = 0; j < 8; j += 4) {
                float4 v = make_float4(acc[i][j], acc[i][j + 1], acc[i][j + 2], acc[i][j + 3]);
                *(float4*)&XW[(size_t)gr * FEAT + tx * 8 + j] = v;
            }
        }
    }
}

// ---------------- gather-propagate: H[c] = dinv[c]^2*XW[c] + sum dinv[c]*dinv[r]*XW[r]
__global__ __launch_bounds__(256) void gather_kernel(const int* __restrict__ off,
                                                     const int* __restrict__ src,
                                                     const float* __restrict__ snrm,
                                                     const float* __restrict__ dinv,
                                                     const float* __restrict__ XW,
                                                     float* __restrict__ H, int n) {
    int node = blockIdx.x * 4 + (threadIdx.x >> 6);
    int lane = threadIdx.x & 63;
    if (node >= n) return;
    float dc = dinv[node];
    float2 v = *(const float2*)&XW[(size_t)node * FEAT + lane * 2];
    float2 acc = make_float2(dc * dc * v.x, dc * dc * v.y);
    int s = off[node], e = off[node + 1];
    for (int i = s; i < e; i++) {
        int r = src[i];
        float nrm = dc * snrm[i];
        float2 u = *(const float2*)&XW[(size_t)r * FEAT + lane * 2];
        acc.x += nrm * u.x;
        acc.y += nrm * u.y;
    }
    *(float2*)&H[(size_t)node * FEAT + lane * 2] = acc;
}

// ---------------- pooling: out[batch[i]] += H[i]; batch is sorted ------------
__global__ __launch_bounds__(128) void pool_kernel(const float* __restrict__ H,
                                                   const int* __restrict__ batch,
                                                   float* __restrict__ out, int n) {
    int t = threadIdx.x;  // feature
    int i0 = blockIdx.x * 512;
    if (i0 >= n) return;
    int i1 = min(i0 + 512, n);
    float acc = 0.f;
    int g = batch[i0];
    for (int i = i0; i < i1; i++) {
        int b = batch[i];
        if (b != g) {
            atomicAdd(&out[(size_t)g * FEAT + t], acc);
            acc = 0.f;
            g = b;
        }
        acc += H[(size_t)i * FEAT + t];
    }
    atomicAdd(&out[(size_t)g * FEAT + t], acc);
}

extern "C" void kernel_launch(void* const* d_in, const int* in_sizes, int n_in,
                              void* d_out, int out_size, void* d_ws, size_t ws_size,
                              hipStream_t stream) {
    const float* x = (const float*)d_in[0];
    const int* ei = (const int*)d_in[1];
    const int* batch = (const int*)d_in[2];
    const float* W0 = (const float*)d_in[3];
    const float* W1 = (const float*)d_in[4];
    const float* W2 = (const float*)d_in[5];
    float* out = (float*)d_out;

    const int N = in_sizes[0] / FEAT;  // 100000
    const int E = in_sizes[1] / 2;     // 640000

    const int* rowI = ei;      // edge_index[0]
    const int* colI = ei + E;  // edge_index[1]

    // workspace layout (all 16B-aligned)
    char* ws = (char*)d_ws;
    auto take = [&](size_t bytes) {
        char* p = ws;
        ws += (bytes + 15) & ~(size_t)15;
        return p;
    };
    int* counts = (int*)take((size_t)N * 4);
    int* off    = (int*)take((size_t)(N + 1) * 4);
    int* nxt    = (int*)take((size_t)N * 4);
    float* dinv = (float*)take((size_t)N * 4);
    int* bsum   = (int*)take(128 * 4);
    int* src    = (int*)take((size_t)E * 4);
    float* snrm = (float*)take((size_t)E * 4);
    float* XW   = (float*)take((size_t)N * FEAT * 4);
    float* H    = (float*)take((size_t)N * FEAT * 4);

    const int nb = (N + 1023) / 1024;  // 98 scan blocks
    const int eb = (E + 255) / 256;

    // ---- degree + CSR build (once per call; edges identical across layers) ----
    hipMemsetAsync(counts, 0, (size_t)N * 4, stream);
    hist_kernel<<<eb, 256, 0, stream>>>(colI, counts, E);
    scan_part<<<nb, 256, 0, stream>>>(counts, bsum, N);
    scan_bsum<<<1, 128, 0, stream>>>(bsum, nb);
    scan_final<<<nb, 256, 0, stream>>>(counts, bsum, off, nxt, dinv, N);
    fill_kernel<<<eb, 256, 0, stream>>>(rowI, colI, dinv, nxt, src, snrm, E);

    const int gemmBlocks = (N + 63) / 64;
    const int gatBlocks = (N + 3) / 4;

    // ---- layer 0 ----
    gemm_kernel<<<gemmBlocks, 256, 0, stream>>>(x, W0, XW, N, 0);
    gather_kernel<<<gatBlocks, 256, 0, stream>>>(off, src, snrm, dinv, XW, H, N);
    // ---- layer 1 ----
    gemm_kernel<<<gemmBlocks, 256, 0, stream>>>(H, W1, XW, N, 0);
    gather_kernel<<<gatBlocks, 256, 0, stream>>>(off, src, snrm, dinv, XW, H, N);
    // ---- layer 2 (leaky_relu fused on GEMM input) ----
    gemm_kernel<<<gemmBlocks, 256, 0, stream>>>(H, W2, XW, N, 1);
    gather_kernel<<<gatBlocks, 256, 0, stream>>>(off, src, snrm, dinv, XW, H, N);

    // ---- global_add_pool ----
    hipMemsetAsync(out, 0, (size_t)out_size * 4, stream);
    pool_kernel<<<(N + 511) / 512, 128, 0, stream>>>(H, batch, out, N);
}

// Round 2
// 404.715 us; speedup vs baseline: 1.8393x; 1.8393x over previous
//
#include <hip/hip_runtime.h>
#include <hip/hip_bf16.h>

#define FEAT 128

typedef unsigned int uint32;
typedef unsigned short ushort16;
typedef __attribute__((ext_vector_type(8))) short short8;
typedef __attribute__((ext_vector_type(4))) float v4f;

// ---- bf16 helpers (RNE round; bf16->f32 is exact shift) ---------------------
__device__ __forceinline__ ushort16 f2bf(float f) {
    uint32 u = __float_as_uint(f);
    u += 0x7fffu + ((u >> 16) & 1u);
    return (ushort16)(u >> 16);
}
__device__ __forceinline__ float bflo(uint32 u) { return __uint_as_float(u << 16); }
__device__ __forceinline__ float bfhi(uint32 u) { return __uint_as_float(u & 0xffff0000u); }

// ---------------- histogram of col (in-degree, without self-loop) ------------
__global__ void hist_kernel(const int* __restrict__ col, int* __restrict__ counts, int E) {
    int e = blockIdx.x * 256 + threadIdx.x;
    if (e < E) atomicAdd(&counts[col[e]], 1);
}

// ---------------- scan step 1: per-1024-chunk sums ---------------------------
__global__ __launch_bounds__(256) void scan_part(const int* __restrict__ counts,
                                                 int* __restrict__ bsum, int n) {
    __shared__ int s[256];
    int base = blockIdx.x * 1024;
    int t = threadIdx.x;
    int v = 0;
#pragma unroll
    for (int i = 0; i < 4; i++) {
        int idx = base + t * 4 + i;
        if (idx < n) v += counts[idx];
    }
    s[t] = v;
    __syncthreads();
    for (int o = 128; o > 0; o >>= 1) {
        if (t < o) s[t] += s[t + o];
        __syncthreads();
    }
    if (t == 0) bsum[blockIdx.x] = s[0];
}

// ---------------- scan step 2: exclusive scan of block sums (nb <= 128) ------
__global__ void scan_bsum(int* __restrict__ bsum, int nb) {
    __shared__ int s[128];
    int t = threadIdx.x;
    int v0 = (t < nb) ? bsum[t] : 0;
    s[t] = v0;
    __syncthreads();
    for (int o = 1; o < 128; o <<= 1) {
        int v = (t >= o) ? s[t - o] : 0;
        __syncthreads();
        s[t] += v;
        __syncthreads();
    }
    if (t < nb) bsum[t] = s[t] - v0;  // exclusive
}

// ---------------- scan step 3: final offsets + next[] + dinv -----------------
__global__ __launch_bounds__(256) void scan_final(const int* __restrict__ counts,
                                                  const int* __restrict__ bsum,
                                                  int* __restrict__ off, int* __restrict__ nxt,
                                                  float* __restrict__ dinv, int n) {
    __shared__ int s[256];
    int base = blockIdx.x * 1024;
    int t = threadIdx.x;
    int c[4];
    int sum = 0;
#pragma unroll
    for (int i = 0; i < 4; i++) {
        int idx = base + t * 4 + i;
        c[i] = (idx < n) ? counts[idx] : 0;
        sum += c[i];
    }
    int v0 = sum;
    s[t] = sum;
    __syncthreads();
    for (int o = 1; o < 256; o <<= 1) {
        int v = (t >= o) ? s[t - o] : 0;
        __syncthreads();
        s[t] += v;
        __syncthreads();
    }
    int excl = s[t] - v0 + bsum[blockIdx.x];
#pragma unroll
    for (int i = 0; i < 4; i++) {
        int idx = base + t * 4 + i;
        if (idx < n) {
            off[idx] = excl;
            nxt[idx] = excl;
            dinv[idx] = rsqrtf((float)(c[i] + 1));  // +1 = self loop
        }
        excl += c[i];
    }
    if (blockIdx.x == gridDim.x - 1 && t == 255) off[n] = excl;  // == E
}

// ---------------- CSR fill: group edges by destination (col) -----------------
__global__ void fill_kernel(const int* __restrict__ row, const int* __restrict__ col,
                            const float* __restrict__ dinv, int* __restrict__ nxt,
                            int* __restrict__ src, float* __restrict__ snrm, int E) {
    int e = blockIdx.x * 256 + threadIdx.x;
    if (e < E) {
        int c = col[e], r = row[e];
        int p = atomicAdd(&nxt[c], 1);
        src[p] = r;
        snrm[p] = dinv[r];
    }
}

// ---------------- convert x (fp32) -> bf16 -----------------------------------
__global__ __launch_bounds__(256) void cvt_x_kernel(const float* __restrict__ x,
                                                    ushort16* __restrict__ Xh, int total4) {
    int id = blockIdx.x * 256 + threadIdx.x;
    if (id >= total4) return;
    const float4 v = *(const float4*)(x + (size_t)id * 4);
    uint2 o;
    o.x = (uint32)f2bf(v.x) | ((uint32)f2bf(v.y) << 16);
    o.y = (uint32)f2bf(v.z) | ((uint32)f2bf(v.w) << 16);
    *(uint2*)(Xh + (size_t)id * 4) = o;
}

// ---------------- convert W0/1/2 (fp32, row-major [k][n]) -> bf16 transposed [n][k]
__global__ __launch_bounds__(256) void cvt_w_kernel(const float* __restrict__ W0,
                                                    const float* __restrict__ W1,
                                                    const float* __restrict__ W2,
                                                    ushort16* __restrict__ Wt) {
    int id = blockIdx.x * 256 + threadIdx.x;
    if (id >= 3 * 16384) return;
    int m = id >> 14;
    int o = id & 16383;
    int ncol = o >> 7;   // output row  (= W column)
    int k = o & 127;     // output col  (= W row)
    const float* W = (m == 0) ? W0 : (m == 1) ? W1 : W2;
    Wt[id] = f2bf(W[(size_t)k * FEAT + ncol]);
}

// ---------------- bf16 MFMA GEMM: Ch = bf16(Ah @ W), W given transposed ------
// Block: 256 thr = 4 waves; 64 rows/block; each wave: 16 rows x 128 cols.
__global__ __launch_bounds__(256) void gemm_mfma(const ushort16* __restrict__ Ah,
                                                 const ushort16* __restrict__ Wt,
                                                 ushort16* __restrict__ Ch, int n) {
    __shared__ ushort16 sW[128 * 136];  // Wt[n][k], padded stride 136 (2-way bank alias = free)

    const int t = threadIdx.x;
    // stage Wt (128x128 bf16 = 32 KB) into LDS
    {
        int r = t >> 1, half = t & 1;
        const ushort16* s = Wt + (size_t)r * 128 + half * 64;
        ushort16* d = sW + r * 136 + half * 64;
#pragma unroll
        for (int i = 0; i < 8; i++)
            *(uint4*)(d + i * 8) = *(const uint4*)(s + i * 8);
    }
    __syncthreads();

    const int w = t >> 6;
    const int lane = t & 63;
    const int quad = lane >> 4;
    const int l16 = lane & 15;
    const int rowBase = blockIdx.x * 64 + w * 16;

    // A fragments: lane holds A[m=l16][k=ks*32+quad*8+j]
    short8 a[4];
    const int arow = rowBase + l16;
    if (arow < n) {
        const ushort16* ap = Ah + (size_t)arow * FEAT + quad * 8;
#pragma unroll
        for (int ks = 0; ks < 4; ks++) a[ks] = *(const short8*)(ap + ks * 32);
    } else {
#pragma unroll
        for (int ks = 0; ks < 4; ks++) a[ks] = (short8)0;
    }

    v4f acc[8];
#pragma unroll
    for (int ct = 0; ct < 8; ct++) acc[ct] = (v4f)0.f;

#pragma unroll
    for (int ct = 0; ct < 8; ct++) {
        const ushort16* bp = sW + (ct * 16 + l16) * 136 + quad * 8;
#pragma unroll
        for (int ks = 0; ks < 4; ks++) {
            short8 b = *(const short8*)(bp + ks * 32);
            acc[ct] = __builtin_amdgcn_mfma_f32_16x16x32_bf16(a[ks], b, acc[ct], 0, 0, 0);
        }
    }

    // store: D layout col=l16, row=quad*4+reg
    const int srow0 = rowBase + quad * 4;
#pragma unroll
    for (int ct = 0; ct < 8; ct++) {
#pragma unroll
        for (int r = 0; r < 4; r++) {
            int row = srow0 + r;
            if (row < n) Ch[(size_t)row * FEAT + ct * 16 + l16] = f2bf(acc[ct][r]);
        }
    }
}

// ---------------- gather-propagate over bf16 table ---------------------------
// H[c] = dinv[c]^2*XW[c] + sum_e dinv[c]*dinv[src_e]*XW[src_e]
// mode 0: write bf16; mode 1: leaky_relu(0.01) then bf16; mode 2: write fp32
__global__ __launch_bounds__(256) void gather_kernel(const int* __restrict__ off,
                                                     const int* __restrict__ src,
                                                     const float* __restrict__ snrm,
                                                     const float* __restrict__ dinv,
                                                     const ushort16* __restrict__ XWh,
                                                     ushort16* __restrict__ Hh,
                                                     float* __restrict__ Hf,
                                                     int n, int mode) {
    int node = blockIdx.x * 4 + (threadIdx.x >> 6);
    int lane = threadIdx.x & 63;
    if (node >= n) return;
    float dc = dinv[node];
    uint32 u = *(const uint32*)(XWh + (size_t)node * FEAT + lane * 2);
    float a0 = dc * dc * bflo(u);
    float a1 = dc * dc * bfhi(u);
    int s = off[node], e = off[node + 1];
    int i = s;
    for (; i + 2 <= e; i += 2) {
        int r0 = src[i], r1 = src[i + 1];
        float n0 = dc * snrm[i], n1 = dc * snrm[i + 1];
        uint32 u0 = *(const uint32*)(XWh + (size_t)r0 * FEAT + lane * 2);
        uint32 u1 = *(const uint32*)(XWh + (size_t)r1 * FEAT + lane * 2);
        a0 += n0 * bflo(u0);
        a1 += n0 * bfhi(u0);
        a0 += n1 * bflo(u1);
        a1 += n1 * bfhi(u1);
    }
    if (i < e) {
        int r0 = src[i];
        float n0 = dc * snrm[i];
        uint32 u0 = *(const uint32*)(XWh + (size_t)r0 * FEAT + lane * 2);
        a0 += n0 * bflo(u0);
        a1 += n0 * bfhi(u0);
    }
    if (mode == 2) {
        *(float2*)(Hf + (size_t)node * FEAT + lane * 2) = make_float2(a0, a1);
    } else {
        if (mode == 1) {
            a0 = (a0 >= 0.f) ? a0 : 0.01f * a0;
            a1 = (a1 >= 0.f) ? a1 : 0.01f * a1;
        }
        uint32 o = (uint32)f2bf(a0) | ((uint32)f2bf(a1) << 16);
        *(uint32*)(Hh + (size_t)node * FEAT + lane * 2) = o;
    }
}

// ---------------- pooling: out[batch[i]] += H[i]; batch sorted ---------------
// 64 rows/block -> 1563 blocks (was 196: latency-starved, 144 us)
__global__ __launch_bounds__(128) void pool_kernel(const float* __restrict__ H,
                                                   const int* __restrict__ batch,
                                                   float* __restrict__ out, int n) {
    int t = threadIdx.x;  // feature
    int i0 = blockIdx.x * 64;
    if (i0 >= n) return;
    int i1 = min(i0 + 64, n);
    float acc = 0.f;
    int g = batch[i0];
    for (int i = i0; i < i1; i++) {
        int b = batch[i];
        if (b != g) {
            atomicAdd(&out[(size_t)g * FEAT + t], acc);
            acc = 0.f;
            g = b;
        }
        acc += H[(size_t)i * FEAT + t];
    }
    atomicAdd(&out[(size_t)g * FEAT + t], acc);
}

extern "C" void kernel_launch(void* const* d_in, const int* in_sizes, int n_in,
                              void* d_out, int out_size, void* d_ws, size_t ws_size,
                              hipStream_t stream) {
    const float* x = (const float*)d_in[0];
    const int* ei = (const int*)d_in[1];
    const int* batch = (const int*)d_in[2];
    const float* W0 = (const float*)d_in[3];
    const float* W1 = (const float*)d_in[4];
    const float* W2 = (const float*)d_in[5];
    float* out = (float*)d_out;

    const int N = in_sizes[0] / FEAT;  // 100000
    const int E = in_sizes[1] / 2;     // 640000

    const int* rowI = ei;
    const int* colI = ei + E;

    char* ws = (char*)d_ws;
    auto take = [&](size_t bytes) {
        char* p = ws;
        ws += (bytes + 15) & ~(size_t)15;
        return p;
    };
    int* counts   = (int*)take((size_t)N * 4);
    int* off      = (int*)take((size_t)(N + 1) * 4);
    int* nxt      = (int*)take((size_t)N * 4);
    float* dinv   = (float*)take((size_t)N * 4);
    int* bsum     = (int*)take(128 * 4);
    int* src      = (int*)take((size_t)E * 4);
    float* snrm   = (float*)take((size_t)E * 4);
    ushort16* Wt  = (ushort16*)take((size_t)3 * 16384 * 2);
    ushort16* Xh  = (ushort16*)take((size_t)N * FEAT * 2);  // }
    ushort16* Hh  = (ushort16*)take((size_t)N * FEAT * 2);  // } adjacent: Hf aliases both
    ushort16* XWh = (ushort16*)take((size_t)N * FEAT * 2);
    float* Hf = (float*)Xh;  // fp32 final H over dead Xh+Hh (both consumed by then)

    const int nb = (N + 1023) / 1024;
    const int eb = (E + 255) / 256;

    // ---- dtype conversions ----
    cvt_w_kernel<<<(3 * 16384 + 255) / 256, 256, 0, stream>>>(W0, W1, W2, Wt);
    cvt_x_kernel<<<(N * FEAT / 4 + 255) / 256, 256, 0, stream>>>(x, Xh, N * FEAT / 4);

    // ---- degree + CSR build ----
    hipMemsetAsync(counts, 0, (size_t)N * 4, stream);
    hist_kernel<<<eb, 256, 0, stream>>>(colI, counts, E);
    scan_part<<<nb, 256, 0, stream>>>(counts, bsum, N);
    scan_bsum<<<1, 128, 0, stream>>>(bsum, nb);
    scan_final<<<nb, 256, 0, stream>>>(counts, bsum, off, nxt, dinv, N);
    fill_kernel<<<eb, 256, 0, stream>>>(rowI, colI, dinv, nxt, src, snrm, E);

    const int gemmBlocks = (N + 63) / 64;
    const int gatBlocks = (N + 3) / 4;

    // ---- layer 0 ----
    gemm_mfma<<<gemmBlocks, 256, 0, stream>>>(Xh, Wt, XWh, N);
    gather_kernel<<<gatBlocks, 256, 0, stream>>>(off, src, snrm, dinv, XWh, Hh, nullptr, N, 0);
    // ---- layer 1 (+leaky on output) ----
    gemm_mfma<<<gemmBlocks, 256, 0, stream>>>(Hh, Wt + 16384, XWh, N);
    gather_kernel<<<gatBlocks, 256, 0, stream>>>(off, src, snrm, dinv, XWh, Hh, nullptr, N, 1);
    // ---- layer 2 (fp32 output for pooling precision) ----
    gemm_mfma<<<gemmBlocks, 256, 0, stream>>>(Hh, Wt + 2 * 16384, XWh, N);
    gather_kernel<<<gatBlocks, 256, 0, stream>>>(off, src, snrm, dinv, XWh, nullptr, Hf, N, 2);

    // ---- global_add_pool ----
    hipMemsetAsync(out, 0, (size_t)out_size * 4, stream);
    pool_kernel<<<(N + 63) / 64, 128, 0, stream>>>(Hf, batch, out, N);
}

// Round 3
// 374.135 us; speedup vs baseline: 1.9896x; 1.0817x over previous
//
#include <hip/hip_runtime.h>
#include <hip/hip_bf16.h>
#include <type_traits>

#define FEAT 128

typedef unsigned int uint32;
typedef unsigned short ushort16;
typedef __attribute__((ext_vector_type(8))) short short8;
typedef __attribute__((ext_vector_type(4))) float v4f;

// ---- bf16 helpers (RNE round; bf16->f32 is exact shift) ---------------------
__device__ __forceinline__ ushort16 f2bf(float f) {
    uint32 u = __float_as_uint(f);
    u += 0x7fffu + ((u >> 16) & 1u);
    return (ushort16)(u >> 16);
}
__device__ __forceinline__ float bflo(uint32 u) { return __uint_as_float(u << 16); }
__device__ __forceinline__ float bfhi(uint32 u) { return __uint_as_float(u & 0xffff0000u); }

// ---------------- histogram of col (in-degree, without self-loop) ------------
__global__ void hist_kernel(const int* __restrict__ col, int* __restrict__ counts, int E) {
    int e = blockIdx.x * 256 + threadIdx.x;
    if (e < E) atomicAdd(&counts[col[e]], 1);
}

// ---------------- scan step 1: per-1024-chunk sums ---------------------------
__global__ __launch_bounds__(256) void scan_part(const int* __restrict__ counts,
                                                 int* __restrict__ bsum, int n) {
    __shared__ int s[256];
    int base = blockIdx.x * 1024;
    int t = threadIdx.x;
    int v = 0;
#pragma unroll
    for (int i = 0; i < 4; i++) {
        int idx = base + t * 4 + i;
        if (idx < n) v += counts[idx];
    }
    s[t] = v;
    __syncthreads();
    for (int o = 128; o > 0; o >>= 1) {
        if (t < o) s[t] += s[t + o];
        __syncthreads();
    }
    if (t == 0) bsum[blockIdx.x] = s[0];
}

// ---------------- scan step 2: exclusive scan of block sums (nb <= 128) ------
__global__ void scan_bsum(int* __restrict__ bsum, int nb) {
    __shared__ int s[128];
    int t = threadIdx.x;
    int v0 = (t < nb) ? bsum[t] : 0;
    s[t] = v0;
    __syncthreads();
    for (int o = 1; o < 128; o <<= 1) {
        int v = (t >= o) ? s[t - o] : 0;
        __syncthreads();
        s[t] += v;
        __syncthreads();
    }
    if (t < nb) bsum[t] = s[t] - v0;  // exclusive
}

// ---------------- scan step 3: final offsets + next[] + dinv -----------------
__global__ __launch_bounds__(256) void scan_final(const int* __restrict__ counts,
                                                  const int* __restrict__ bsum,
                                                  int* __restrict__ off, int* __restrict__ nxt,
                                                  float* __restrict__ dinv, int n) {
    __shared__ int s[256];
    int base = blockIdx.x * 1024;
    int t = threadIdx.x;
    int c[4];
    int sum = 0;
#pragma unroll
    for (int i = 0; i < 4; i++) {
        int idx = base + t * 4 + i;
        c[i] = (idx < n) ? counts[idx] : 0;
        sum += c[i];
    }
    int v0 = sum;
    s[t] = sum;
    __syncthreads();
    for (int o = 1; o < 256; o <<= 1) {
        int v = (t >= o) ? s[t - o] : 0;
        __syncthreads();
        s[t] += v;
        __syncthreads();
    }
    int excl = s[t] - v0 + bsum[blockIdx.x];
#pragma unroll
    for (int i = 0; i < 4; i++) {
        int idx = base + t * 4 + i;
        if (idx < n) {
            off[idx] = excl;
            nxt[idx] = excl;
            dinv[idx] = rsqrtf((float)(c[i] + 1));  // +1 = self loop
        }
        excl += c[i];
    }
    if (blockIdx.x == gridDim.x - 1 && t == 255) off[n] = excl;  // == E
}

// ---------------- CSR fill: group edges by destination (col) -----------------
__global__ void fill_kernel(const int* __restrict__ row, const int* __restrict__ col,
                            const float* __restrict__ dinv, int* __restrict__ nxt,
                            int* __restrict__ src, float* __restrict__ snrm, int E) {
    int e = blockIdx.x * 256 + threadIdx.x;
    if (e < E) {
        int c = col[e], r = row[e];
        int p = atomicAdd(&nxt[c], 1);
        src[p] = r;
        snrm[p] = dinv[r];
    }
}

// ---------------- convert W0/1/2 (fp32, row-major [k][n]) -> bf16 transposed [n][k]
__global__ __launch_bounds__(256) void cvt_w_kernel(const float* __restrict__ W0,
                                                    const float* __restrict__ W1,
                                                    const float* __restrict__ W2,
                                                    ushort16* __restrict__ Wt) {
    int id = blockIdx.x * 256 + threadIdx.x;
    if (id >= 3 * 16384) return;
    int m = id >> 14;
    int o = id & 16383;
    int ncol = o >> 7;   // output row  (= W column)
    int k = o & 127;     // output col  (= W row)
    const float* W = (m == 0) ? W0 : (m == 1) ? W1 : W2;
    Wt[id] = f2bf(W[(size_t)k * FEAT + ncol]);
}

// ---------------- bf16 MFMA GEMM: Ch = bf16(A @ W), W given transposed -------
// A is fp32 (layer 0, fused convert) or bf16. 256 thr = 4 waves; 64 rows/block.
// Epilogue: MFMA C-layout -> LDS (XOR-chunk swizzle) -> 16B coalesced stores.
template <typename T>
__global__ __launch_bounds__(256) void gemm_mfma(const T* __restrict__ A,
                                                 const ushort16* __restrict__ Wt,
                                                 ushort16* __restrict__ Ch, int n) {
    __shared__ ushort16 sW[128 * 136];     // Wt[n][k], stride 136 (2-way alias = free)
    __shared__ ushort16 sOut[4 * 2048];    // per-wave 16x128 output tile

    const int t = threadIdx.x;
    // stage Wt (128x128 bf16 = 32 KB) into LDS
    {
        int r = t >> 1, half = t & 1;
        const ushort16* s = Wt + (size_t)r * 128 + half * 64;
        ushort16* d = sW + r * 136 + half * 64;
#pragma unroll
        for (int i = 0; i < 8; i++)
            *(uint4*)(d + i * 8) = *(const uint4*)(s + i * 8);
    }
    __syncthreads();

    const int w = t >> 6;
    const int lane = t & 63;
    const int quad = lane >> 4;
    const int l16 = lane & 15;
    const int rowBase = blockIdx.x * 64 + w * 16;

    // A fragments: lane holds A[m=l16][k=ks*32+quad*8+j]
    short8 a[4];
    const int arow = rowBase + l16;
    if (arow < n) {
        if constexpr (std::is_same<T, float>::value) {
#pragma unroll
            for (int ks = 0; ks < 4; ks++) {
                const float* ap = A + (size_t)arow * FEAT + quad * 8 + ks * 32;
                float4 f0 = *(const float4*)ap;
                float4 f1 = *(const float4*)(ap + 4);
                short8 v;
                v[0] = f2bf(f0.x); v[1] = f2bf(f0.y); v[2] = f2bf(f0.z); v[3] = f2bf(f0.w);
                v[4] = f2bf(f1.x); v[5] = f2bf(f1.y); v[6] = f2bf(f1.z); v[7] = f2bf(f1.w);
                a[ks] = v;
            }
        } else {
            const ushort16* ap = A + (size_t)arow * FEAT + quad * 8;
#pragma unroll
            for (int ks = 0; ks < 4; ks++) a[ks] = *(const short8*)(ap + ks * 32);
        }
    } else {
#pragma unroll
        for (int ks = 0; ks < 4; ks++) a[ks] = (short8)0;
    }

    v4f acc[8];
#pragma unroll
    for (int ct = 0; ct < 8; ct++) acc[ct] = (v4f)0.f;

#pragma unroll
    for (int ct = 0; ct < 8; ct++) {
        const ushort16* bp = sW + (ct * 16 + l16) * 136 + quad * 8;
#pragma unroll
        for (int ks = 0; ks < 4; ks++) {
            short8 b = *(const short8*)(bp + ks * 32);
            acc[ct] = __builtin_amdgcn_mfma_f32_16x16x32_bf16(a[ks], b, acc[ct], 0, 0, 0);
        }
    }

    // ---- epilogue: repack via LDS, then coalesced 16B stores ----
    // value (ct,r) lives at local row rloc=quad*4+r, col c=ct*16+l16.
    // chunk(c) = c>>3; store at chunk' = chunk ^ rloc (bank-spread), invert on read.
    ushort16* so = sOut + w * 2048;
#pragma unroll
    for (int ct = 0; ct < 8; ct++) {
#pragma unroll
        for (int r = 0; r < 4; r++) {
            int rloc = quad * 4 + r;
            int chSt = ((ct * 2) + (l16 >> 3)) ^ rloc;
            so[rloc * 128 + chSt * 8 + (l16 & 7)] = f2bf(acc[ct][r]);
        }
    }
    // wave-private LDS region: no barrier needed (wave-coherent)
#pragma unroll
    for (int p = 0; p < 4; p++) {
        int idx = p * 64 + lane;
        int lr = idx >> 4;   // local row 0..15
        int m = idx & 15;    // logical chunk
        int row = rowBase + lr;
        if (row < n)
            *(uint4*)(Ch + (size_t)row * FEAT + m * 8) =
                *(const uint4*)(so + lr * 128 + ((m ^ lr) * 8));
    }
}

// ---------------- gather-propagate over bf16 table ---------------------------
// H[c] = dinv[c]^2*XW[c] + sum_e dinv[c]*dinv[src_e]*XW[src_e]
// 4 edge-groups x 16 lanes; 16B row loads; butterfly combine across groups.
// mode 0: write bf16; mode 1: leaky_relu(0.01) then bf16; mode 2: write fp32
__global__ __launch_bounds__(256) void gather_kernel(const int* __restrict__ off,
                                                     const int* __restrict__ src,
                                                     const float* __restrict__ snrm,
                                                     const float* __restrict__ dinv,
                                                     const ushort16* __restrict__ XWh,
                                                     ushort16* __restrict__ Hh,
                                                     float* __restrict__ Hf,
                                                     int n, int mode) {
    int node = blockIdx.x * 4 + (threadIdx.x >> 6);
    if (node >= n) return;
    int lane = threadIdx.x & 63;
    int grp = lane >> 4;   // edge group 0..3
    int l16 = lane & 15;   // 16B chunk within row
    float dc = dinv[node];
    const uint4* table = (const uint4*)XWh;  // row = 16 x uint4

    float acc[8];
    if (grp == 0) {  // self-loop term (group 0 only)
        uint4 v = table[(size_t)node * 16 + l16];
        float w0 = dc * dc;
        acc[0] = w0 * bflo(v.x); acc[1] = w0 * bfhi(v.x);
        acc[2] = w0 * bflo(v.y); acc[3] = w0 * bfhi(v.y);
        acc[4] = w0 * bflo(v.z); acc[5] = w0 * bfhi(v.z);
        acc[6] = w0 * bflo(v.w); acc[7] = w0 * bfhi(v.w);
    } else {
#pragma unroll
        for (int j = 0; j < 8; j++) acc[j] = 0.f;
    }

    int s = off[node], e = off[node + 1];
    for (int i = s + grp; i < e; i += 4) {
        int r = src[i];
        float nrm = dc * snrm[i];
        uint4 u = table[(size_t)r * 16 + l16];
        acc[0] += nrm * bflo(u.x); acc[1] += nrm * bfhi(u.x);
        acc[2] += nrm * bflo(u.y); acc[3] += nrm * bfhi(u.y);
        acc[4] += nrm * bflo(u.z); acc[5] += nrm * bfhi(u.z);
        acc[6] += nrm * bflo(u.w); acc[7] += nrm * bfhi(u.w);
    }

    // combine the 4 groups (lane bits 4,5)
#pragma unroll
    for (int j = 0; j < 8; j++) {
        acc[j] += __shfl_xor(acc[j], 16);
        acc[j] += __shfl_xor(acc[j], 32);
    }

    if (mode == 2) {
        if (grp < 2) {
            float4 o = (grp == 0) ? make_float4(acc[0], acc[1], acc[2], acc[3])
                                  : make_float4(acc[4], acc[5], acc[6], acc[7]);
            *(float4*)(Hf + (size_t)node * FEAT + l16 * 8 + grp * 4) = o;
        }
    } else {
        if (mode == 1) {
#pragma unroll
            for (int j = 0; j < 8; j++) acc[j] = (acc[j] >= 0.f) ? acc[j] : 0.01f * acc[j];
        }
        if (grp == 0) {
            uint4 o;
            o.x = (uint32)f2bf(acc[0]) | ((uint32)f2bf(acc[1]) << 16);
            o.y = (uint32)f2bf(acc[2]) | ((uint32)f2bf(acc[3]) << 16);
            o.z = (uint32)f2bf(acc[4]) | ((uint32)f2bf(acc[5]) << 16);
            o.w = (uint32)f2bf(acc[6]) | ((uint32)f2bf(acc[7]) << 16);
            *(uint4*)(Hh + (size_t)node * FEAT + l16 * 8) = o;
        }
    }
}

// ---------------- pooling: out[batch[i]] += H[i]; batch sorted ---------------
__global__ __launch_bounds__(128) void pool_kernel(const float* __restrict__ H,
                                                   const int* __restrict__ batch,
                                                   float* __restrict__ out, int n) {
    int t = threadIdx.x;  // feature
    int i0 = blockIdx.x * 64;
    if (i0 >= n) return;
    int i1 = min(i0 + 64, n);
    float acc = 0.f;
    int g = batch[i0];
    for (int i = i0; i < i1; i++) {
        int b = batch[i];
        if (b != g) {
            atomicAdd(&out[(size_t)g * FEAT + t], acc);
            acc = 0.f;
            g = b;
        }
        acc += H[(size_t)i * FEAT + t];
    }
    atomicAdd(&out[(size_t)g * FEAT + t], acc);
}

extern "C" void kernel_launch(void* const* d_in, const int* in_sizes, int n_in,
                              void* d_out, int out_size, void* d_ws, size_t ws_size,
                              hipStream_t stream) {
    const float* x = (const float*)d_in[0];
    const int* ei = (const int*)d_in[1];
    const int* batch = (const int*)d_in[2];
    const float* W0 = (const float*)d_in[3];
    const float* W1 = (const float*)d_in[4];
    const float* W2 = (const float*)d_in[5];
    float* out = (float*)d_out;

    const int N = in_sizes[0] / FEAT;  // 100000
    const int E = in_sizes[1] / 2;     // 640000

    const int* rowI = ei;
    const int* colI = ei + E;

    char* ws = (char*)d_ws;
    auto take = [&](size_t bytes) {
        char* p = ws;
        ws += (bytes + 15) & ~(size_t)15;
        return p;
    };
    int* counts   = (int*)take((size_t)N * 4);
    int* off      = (int*)take((size_t)(N + 1) * 4);
    int* nxt      = (int*)take((size_t)N * 4);
    float* dinv   = (float*)take((size_t)N * 4);
    int* bsum     = (int*)take(128 * 4);
    int* src      = (int*)take((size_t)E * 4);
    float* snrm   = (float*)take((size_t)E * 4);
    ushort16* Wt  = (ushort16*)take((size_t)3 * 16384 * 2);
    ushort16* Hh  = (ushort16*)take((size_t)N * FEAT * 2);  // } adjacent:
    ushort16* XWh = (ushort16*)take((size_t)N * FEAT * 2);  // } Hf aliases both
    float* Hf = (float*)Hh;  // fp32 final H over dead Hh+XWh area... careful: see below

    const int nb = (N + 1023) / 1024;
    const int eb = (E + 255) / 256;

    // ---- weights -> bf16 transposed ----
    cvt_w_kernel<<<(3 * 16384 + 255) / 256, 256, 0, stream>>>(W0, W1, W2, Wt);

    // ---- degree + CSR build ----
    hipMemsetAsync(counts, 0, (size_t)N * 4, stream);
    hist_kernel<<<eb, 256, 0, stream>>>(colI, counts, E);
    scan_part<<<nb, 256, 0, stream>>>(counts, bsum, N);
    scan_bsum<<<1, 128, 0, stream>>>(bsum, nb);
    scan_final<<<nb, 256, 0, stream>>>(counts, bsum, off, nxt, dinv, N);
    fill_kernel<<<eb, 256, 0, stream>>>(rowI, colI, dinv, nxt, src, snrm, E);

    const int gemmBlocks = (N + 63) / 64;
    const int gatBlocks = (N + 3) / 4;

    // ---- layer 0 (x fp32 -> bf16 fused in GEMM) ----
    gemm_mfma<float><<<gemmBlocks, 256, 0, stream>>>(x, Wt, XWh, N);
    gather_kernel<<<gatBlocks, 256, 0, stream>>>(off, src, snrm, dinv, XWh, Hh, nullptr, N, 0);
    // ---- layer 1 (+leaky on output) ----
    gemm_mfma<ushort16><<<gemmBlocks, 256, 0, stream>>>(Hh, Wt + 16384, XWh, N);
    gather_kernel<<<gatBlocks, 256, 0, stream>>>(off, src, snrm, dinv, XWh, Hh, nullptr, N, 1);
    // ---- layer 2 (fp32 output for pooling precision) ----
    gemm_mfma<ushort16><<<gemmBlocks, 256, 0, stream>>>(Hh, Wt + 2 * 16384, XWh, N);
    // Hf overlays Hh+XWh: gather mode 2 reads XWh rows and writes Hf[node].
    // Hf[node] spans bytes [node*512, node*512+512) of Hh-base; XWh starts at
    // byte N*256. Write to Hf[node] touches XWh row region 2*node - N .. 2*node+1 - N,
    // i.e. rows < node are never overwritten before... NOT safe in general
    // (node > N/2 writes into XWh rows 2*node-N >= node only when node >= N).
    // 2*node - N < node  <=>  node < N. So writes can clobber XWh rows BELOW the
    // write frontier that other blocks still read. Use separate fp32 region instead.
    {
        float* HfSep = (float*)take((size_t)N * FEAT * 4);
        gather_kernel<<<gatBlocks, 256, 0, stream>>>(off, src, snrm, dinv, XWh, nullptr, HfSep, N, 2);
        hipMemsetAsync(out, 0, (size_t)out_size * 4, stream);
        pool_kernel<<<(N + 63) / 64, 128, 0, stream>>>(HfSep, batch, out, N);
    }
}